// Round 12
// baseline (229.543 us; speedup 1.0000x reference)
//
#include <hip/hip_runtime.h>
#include <hip/hip_bf16.h>
#include <stdint.h>

// MHA fused pipeline, MI355X gfx950.
// B=4 S=2048 D=1024 H=16 DK=64.  fp32 in/out, bf16 MFMA internally.
//
// ws layout (bytes):
//   [0,        8388608)   wbf   : bf16 weights [4][1024][1024] order q,k,v,o
//   [8388608,  25165824)  Qh    : bf16 [B,H,S,DK]  (Q pre-scaled by 0.125*log2e)
//   [25165824, 41943040)  Kh    : bf16 [B,H,S,DK]
//   [41943040, 58720256)  Vh    : bf16 [B,H,S,DK]
//   [58720256, 75497472)  AO    : bf16, DUAL USE:
//       phase 1 (QKV): staging for X_z cast to bf16 [8192][1024] (exactly 16MB)
//       phase 2 (attn/out): attention output [B,S,D]
//
// XCD note: with gridDim.x==8, blockIdx.x == lin%8 selects the XCD; blocks
// sharing an A panel co-reside on one XCD (panel L2-hit). (round-6 win)
//
// NUMERICS: all f32->bf16 in reduction-feeding paths use explicit RNE bit math
// (== __float2bfloat16 for finite inputs). v_cvt_pk_bf16_f32 is NOT RNE
// (round-7 regression). RULE#20: no runtime-indexed register arrays (round-8).
//
// GEMM structure (round-12): ALL GEMMs are the proven round-10 bf16 form —
// 128x128 tile, BK=64, single-buffer, global_load_lds both operands, 16B-chunk
// swizzle physical = logical ^ (row&7), zero bank conflicts measured. The fp32
// A path (round-11 bottleneck: VALU pack in-loop) is gone: X is pre-cast once.

using f32x4  = __attribute__((ext_vector_type(4))) float;
using f32x16 = __attribute__((ext_vector_type(16))) float;
using s16x8  = __attribute__((ext_vector_type(8))) short;
using u16x8  = __attribute__((ext_vector_type(8))) unsigned short;
using u16x4  = __attribute__((ext_vector_type(4))) unsigned short;

#define MFMA16(a, b, c) __builtin_amdgcn_mfma_f32_16x16x32_bf16((a), (b), (c), 0, 0, 0)
#define MFMA32(a, b, c) __builtin_amdgcn_mfma_f32_32x32x16_bf16((a), (b), (c), 0, 0, 0)

#define GLL16(gptr, lptr)                                                      \
  __builtin_amdgcn_global_load_lds(                                            \
      (const __attribute__((address_space(1))) void*)(gptr),                   \
      (__attribute__((address_space(3))) void*)(lptr), 16, 0, 0)

__device__ __forceinline__ unsigned short f2bf(float f) {
  union { __hip_bfloat16 h; unsigned short u; } cv;
  cv.h = __float2bfloat16(f);
  return cv.u;
}

// explicit RNE f32->bf16 pair pack (bit-identical to __float2bfloat16, finite)
__device__ __forceinline__ unsigned int pkrne(float a, float b) {
  unsigned int ua = __builtin_bit_cast(unsigned int, a);
  unsigned int ub = __builtin_bit_cast(unsigned int, b);
  ua = ua + 0x7FFFu + ((ua >> 16) & 1u);
  ub = ub + 0x7FFFu + ((ub >> 16) & 1u);
  return (ua >> 16) | (ub & 0xFFFF0000u);
}

__device__ __forceinline__ float exp2a(float x) {
  return __builtin_amdgcn_exp2f(x);
}

// ---------------------------------------------------------------- cast weights
__global__ __launch_bounds__(256) void cast_w_kernel(
    const float* __restrict__ wq, const float* __restrict__ wk,
    const float* __restrict__ wv, const float* __restrict__ wo,
    unsigned short* __restrict__ dst) {
  int i = blockIdx.x * 256 + threadIdx.x;  // float4 index, total 1M
  int m = i >> 18;
  int off = i & 0x3FFFF;
  const float* src = (m == 0) ? wq : (m == 1) ? wk : (m == 2) ? wv : wo;
  float4 v = reinterpret_cast<const float4*>(src)[off];
  u16x4 o;
  o[0] = f2bf(v.x); o[1] = f2bf(v.y); o[2] = f2bf(v.z); o[3] = f2bf(v.w);
  *reinterpret_cast<u16x4*>(dst + (size_t)i * 4) = o;
}

// ------------------------------------------------------------ cast activations
// fp32 [8192][1024] -> bf16, RNE. 2M float4 -> 8192 blocks x 256 threads.
__global__ __launch_bounds__(256) void cast_x_kernel(
    const float* __restrict__ src, unsigned short* __restrict__ dst) {
  int i = blockIdx.x * 256 + threadIdx.x;  // float4 index
  float4 v = reinterpret_cast<const float4*>(src)[i];
  uint2 p;
  p.x = pkrne(v.x, v.y);
  p.y = pkrne(v.z, v.w);
  *reinterpret_cast<uint2*>(dst + (size_t)i * 4) = p;
}

// --------------------------------------------------------- QKV projection (bf16)
// C = Xbf(bf16)[8192,1024] @ W(bf16,[N,K]) + bias -> [B,H,S,DK] bf16 scatter.
// Identical staging/compute structure to gemm_out (BK=64, GLL16 both, zero
// conflicts); only the epilogue differs (head scatter + qscale).
__global__ __launch_bounds__(256) void gemm_qkvz_kernel(
    const unsigned short* __restrict__ Xbf, const unsigned short* __restrict__ W,
    const float* __restrict__ bias, unsigned short* __restrict__ dst,
    float qscale) {
  __shared__ __align__(16) unsigned short Asm_[128 * 64];
  __shared__ __align__(16) unsigned short Bsm_[128 * 64];

  const int t = threadIdx.x;
  const int lane = t & 63, w = t >> 6;
  const int g = lane >> 4, c = lane & 15;
  const int wm = (w >> 1) * 64, wn = (w & 1) * 64;
  const int n0 = (blockIdx.y & 7) * 128;
  const int m0 = (blockIdx.x * 8 + (blockIdx.y >> 3)) * 128;

  f32x4 acc[4][4];
#pragma unroll
  for (int i = 0; i < 4; i++)
#pragma unroll
    for (int j = 0; j < 4; j++) acc[i][j] = (f32x4)0.0f;

  const int blr = lane >> 3;
  const int bgc = (lane & 7) ^ blr;

  for (int kt = 0; kt < 16; ++kt) {
    const int k0 = kt * 64;
    __syncthreads();
#pragma unroll
    for (int i = 0; i < 4; i++) {
      int ii = w * 4 + i;
      const unsigned short* ga = Xbf + (size_t)(m0 + ii * 8 + blr) * 1024 + k0 + bgc * 8;
      GLL16(ga, &Asm_[ii * 512]);
      const unsigned short* gb = W + (size_t)(n0 + ii * 8 + blr) * 1024 + k0 + bgc * 8;
      GLL16(gb, &Bsm_[ii * 512]);
    }
    __syncthreads();

#pragma unroll
    for (int ks = 0; ks < 2; ks++) {
      s16x8 af[4], bfr[4];
#pragma unroll
      for (int mt = 0; mt < 4; mt++) {
        int r = wm + mt * 16 + c;
        af[mt] = *reinterpret_cast<const s16x8*>(&Asm_[r * 64 + (((ks * 4 + g) ^ (c & 7)) << 3)]);
      }
#pragma unroll
      for (int nt = 0; nt < 4; nt++) {
        int r = wn + nt * 16 + c;
        bfr[nt] = *reinterpret_cast<const s16x8*>(&Bsm_[r * 64 + (((ks * 4 + g) ^ (c & 7)) << 3)]);
      }
#pragma unroll
      for (int mt = 0; mt < 4; mt++)
#pragma unroll
        for (int nt = 0; nt < 4; nt++)
          acc[mt][nt] = MFMA16(af[mt], bfr[nt], acc[mt][nt]);
    }
  }

  // epilogue: +bias, *qscale, scatter to [B,H,S,DK] bf16
#pragma unroll
  for (int mt = 0; mt < 4; mt++)
#pragma unroll
    for (int nt = 0; nt < 4; nt++) {
      int n = n0 + wn + nt * 16 + c;
      float bb = bias[n];
      int h = n >> 6, dk = n & 63;
#pragma unroll
      for (int r = 0; r < 4; r++) {
        int m = m0 + wm + mt * 16 + g * 4 + r;
        int b = m >> 11, s = m & 2047;
        dst[(((size_t)b * 16 + h) * 2048 + s) * 64 + dk] =
            f2bf((acc[mt][nt][r] + bb) * qscale);
      }
    }
}

// ----------------------------------------------------------- output projection
// out(fp32)[8192,1024] = AO(bf16) @ Wo(bf16,[N,K]) + bo.  BK=64, GLL16 both.
// (round-10 form: zero bank conflicts)
__global__ __launch_bounds__(256) void gemm_out_kernel(
    const unsigned short* __restrict__ AO, const unsigned short* __restrict__ Wo,
    const float* __restrict__ bo, float* __restrict__ out) {
  __shared__ __align__(16) unsigned short Asm_[128 * 64];
  __shared__ __align__(16) unsigned short Bsm_[128 * 64];

  const int t = threadIdx.x;
  const int lane = t & 63, w = t >> 6;
  const int g = lane >> 4, c = lane & 15;
  const int wm = (w >> 1) * 64, wn = (w & 1) * 64;
  const int n0 = (blockIdx.y & 7) * 128;
  const int m0 = (blockIdx.x * 8 + (blockIdx.y >> 3)) * 128;

  f32x4 acc[4][4];
#pragma unroll
  for (int i = 0; i < 4; i++)
#pragma unroll
    for (int j = 0; j < 4; j++) acc[i][j] = (f32x4)0.0f;

  const int blr = lane >> 3;
  const int bgc = (lane & 7) ^ blr;

  for (int kt = 0; kt < 16; ++kt) {
    const int k0 = kt * 64;
    __syncthreads();
#pragma unroll
    for (int i = 0; i < 4; i++) {
      int ii = w * 4 + i;
      const unsigned short* ga = AO + (size_t)(m0 + ii * 8 + blr) * 1024 + k0 + bgc * 8;
      GLL16(ga, &Asm_[ii * 512]);
      const unsigned short* gb = Wo + (size_t)(n0 + ii * 8 + blr) * 1024 + k0 + bgc * 8;
      GLL16(gb, &Bsm_[ii * 512]);
    }
    __syncthreads();

#pragma unroll
    for (int ks = 0; ks < 2; ks++) {
      s16x8 af[4], bfr[4];
#pragma unroll
      for (int mt = 0; mt < 4; mt++) {
        int r = wm + mt * 16 + c;
        af[mt] = *reinterpret_cast<const s16x8*>(&Asm_[r * 64 + (((ks * 4 + g) ^ (c & 7)) << 3)]);
      }
#pragma unroll
      for (int nt = 0; nt < 4; nt++) {
        int r = wn + nt * 16 + c;
        bfr[nt] = *reinterpret_cast<const s16x8*>(&Bsm_[r * 64 + (((ks * 4 + g) ^ (c & 7)) << 3)]);
      }
#pragma unroll
      for (int mt = 0; mt < 4; mt++)
#pragma unroll
        for (int nt = 0; nt < 4; nt++)
          acc[mt][nt] = MFMA16(af[mt], bfr[nt], acc[mt][nt]);
    }
  }

#pragma unroll
  for (int mt = 0; mt < 4; mt++)
#pragma unroll
    for (int nt = 0; nt < 4; nt++) {
      int n = n0 + wn + nt * 16 + c;
      float bb = bo[n];
#pragma unroll
      for (int r = 0; r < 4; r++) {
        int m = m0 + wm + mt * 16 + g * 4 + r;
        out[(size_t)m * 1024 + n] = acc[mt][nt][r] + bb;
      }
    }
}

// ---------------------------------------------------------------- attention v4
// (unchanged from round 9 — passing, ~55us)
__global__ __launch_bounds__(512) void attn_kernel(
    const unsigned short* __restrict__ Qh, const unsigned short* __restrict__ Kh,
    const unsigned short* __restrict__ Vh, unsigned short* __restrict__ AO) {
  const int bh = blockIdx.x * 8 + (blockIdx.y >> 3);
  const int b = bh >> 4, h = bh & 15;
  const int q0 = (blockIdx.y & 7) * 256;
  const int t = threadIdx.x, lane = t & 63, w = t >> 6;
  const int lo = lane & 31, hi = lane >> 5;

  __shared__ __align__(16) unsigned short Ks[2][64 * 64];
  __shared__ __align__(16) unsigned short Vt[2][64 * 64];

  const size_t kvbase = (size_t)bh * 2048 * 64;

  s16x8 qb[4];
  {
    const unsigned short* qp = Qh + kvbase + (size_t)(q0 + w * 32 + lo) * 64;
#pragma unroll
    for (int ks = 0; ks < 4; ks++)
      qb[ks] = *reinterpret_cast<const s16x8*>(qp + ks * 16 + hi * 8);
  }

  f32x16 oacc[2];
  oacc[0] = (f32x16)0.0f; oacc[1] = (f32x16)0.0f;
  float lsum = 0.0f;

  const int skrow = t >> 3, sks = t & 7;
  const int kgc = sks ^ (skrow & 7) ^ w;
  const int vkrow = t >> 3, vd0 = (t & 7) * 8;
  const int vwc = w ^ (t & 7);
  const int vcl = vkrow & 7;

  const int rx0 = (lo & 7) ^ (lo >> 3);
  const int rx1 = (lo & 7) ^ (4 | (lo >> 3));

  uint4 kk, vv;
  kk = *reinterpret_cast<const uint4*>(Kh + kvbase + (size_t)skrow * 64 + kgc * 8);
  vv = *reinterpret_cast<const uint4*>(Vh + kvbase + (size_t)vkrow * 64 + vd0);
  *reinterpret_cast<uint4*>(&Ks[0][(size_t)t * 8]) = kk;
  {
    const unsigned short* vs = reinterpret_cast<const unsigned short*>(&vv);
#pragma unroll
    for (int j = 0; j < 8; j++)
      Vt[0][(vd0 + j) * 64 + ((vwc ^ j) << 3) + vcl] = vs[j];
  }

  for (int it = 0; it < 32; ++it) {
    const int cur = it & 1, nxt = cur ^ 1;
    const bool more = (it < 31);
    if (more) {
      const int kv = (it + 1) * 64;
      kk = *reinterpret_cast<const uint4*>(Kh + kvbase + (size_t)(kv + skrow) * 64 + kgc * 8);
      vv = *reinterpret_cast<const uint4*>(Vh + kvbase + (size_t)(kv + vkrow) * 64 + vd0);
    }
    __syncthreads();

    f32x16 st[2];
    st[0] = (f32x16)0.0f; st[1] = (f32x16)0.0f;
#pragma unroll
    for (int kb = 0; kb < 2; kb++) {
      const int rx = kb ? rx1 : rx0;
#pragma unroll
      for (int ks = 0; ks < 4; ks++) {
        s16x8 ka = *reinterpret_cast<const s16x8*>(
            &Ks[cur][(kb * 32 + lo) * 64 + (((ks * 2 + hi) ^ rx) << 3)]);
        st[kb] = MFMA32(ka, qb[ks], st[kb]);
      }
    }

    s16x8 pa[4];
    float s0 = 0.0f, s1 = 0.0f, s2 = 0.0f, s3 = 0.0f;
#pragma unroll
    for (int kb = 0; kb < 2; kb++) {
      float e[16];
#pragma unroll
      for (int r = 0; r < 16; r += 4) {
        e[r]     = exp2a(st[kb][r]);
        e[r + 1] = exp2a(st[kb][r + 1]);
        e[r + 2] = exp2a(st[kb][r + 2]);
        e[r + 3] = exp2a(st[kb][r + 3]);
        s0 += e[r]; s1 += e[r + 1]; s2 += e[r + 2]; s3 += e[r + 3];
      }
#pragma unroll
      for (int half = 0; half < 2; half++) {
        const float* eb = e + half * 8;
        unsigned int x1 = pkrne(eb[0], eb[1]);
        unsigned int x2 = pkrne(eb[2], eb[3]);
        unsigned int y1 = pkrne(eb[4], eb[5]);
        unsigned int y2 = pkrne(eb[6], eb[7]);
        asm volatile("v_permlane32_swap_b32 %0, %1" : "+v"(x1), "+v"(y1));
        asm volatile("v_permlane32_swap_b32 %0, %1" : "+v"(x2), "+v"(y2));
        uint4 u;
        u.x = x1; u.y = x2; u.z = y1; u.w = y2;
        pa[kb * 2 + half] = *reinterpret_cast<const s16x8*>(&u);
      }
    }
    lsum += (s0 + s1) + (s2 + s3);

    if (more) {
      *reinterpret_cast<uint4*>(&Ks[nxt][(size_t)t * 8]) = kk;
      const unsigned short* vs = reinterpret_cast<const unsigned short*>(&vv);
#pragma unroll
      for (int j = 0; j < 8; j++)
        Vt[nxt][(vd0 + j) * 64 + ((vwc ^ j) << 3) + vcl] = vs[j];
    }

#pragma unroll
    for (int ks = 0; ks < 4; ks++)
#pragma unroll
      for (int db = 0; db < 2; db++) {
        const int rx = db ? rx1 : rx0;
        s16x8 vb = *reinterpret_cast<const s16x8*>(
            &Vt[cur][(db * 32 + lo) * 64 + (((ks * 2 + hi) ^ rx) << 3)]);
        oacc[db] = MFMA32(pa[ks], vb, oacc[db]);
      }
  }

  float ltot = lsum + __shfl_xor(lsum, 32);
  float linv = 1.0f / ltot;
#pragma unroll
  for (int r = 0; r < 16; r++) {
    int qr = (r & 3) + ((r >> 2) << 3) + (hi << 2);
    float inv_r = __shfl(linv, qr);
    int srow = q0 + w * 32 + qr;
    size_t obase = ((size_t)b * 2048 + srow) * 1024 + (size_t)h * 64;
    AO[obase + lo]      = f2bf(oacc[0][r] * inv_r);
    AO[obase + 32 + lo] = f2bf(oacc[1][r] * inv_r);
  }
}

// ---------------------------------------------------------------- launcher
extern "C" void kernel_launch(void* const* d_in, const int* in_sizes, int n_in,
                              void* d_out, int out_size, void* d_ws, size_t ws_size,
                              hipStream_t stream) {
  const float* query = (const float*)d_in[0];
  const float* key   = (const float*)d_in[1];
  const float* value = (const float*)d_in[2];
  const float* Wq = (const float*)d_in[3];
  const float* bq = (const float*)d_in[4];
  const float* Wk = (const float*)d_in[5];
  const float* bk = (const float*)d_in[6];
  const float* Wv = (const float*)d_in[7];
  const float* bv = (const float*)d_in[8];
  const float* Wo = (const float*)d_in[9];
  const float* bo = (const float*)d_in[10];

  uint8_t* wsb = (uint8_t*)d_ws;
  unsigned short* wbf = (unsigned short*)wsb;                      // 4 x 1M bf16
  unsigned short* Qh  = (unsigned short*)(wsb + 8388608);
  unsigned short* Kh  = (unsigned short*)(wsb + 8388608 + 16777216);
  unsigned short* Vh  = (unsigned short*)(wsb + 8388608 + 2 * 16777216);
  unsigned short* AO  = (unsigned short*)(wsb + 8388608 + 3 * 16777216);
  // AO region doubles as the bf16 X staging buffer during the QKV phase
  unsigned short* Xbf = AO;

  const float QSCALE = 0.18033688011112042f;  // 0.125 * log2(e)

  cast_w_kernel<<<dim3(4096), dim3(256), 0, stream>>>(Wq, Wk, Wv, Wo, wbf);

  // q
  cast_x_kernel<<<dim3(8192), dim3(256), 0, stream>>>(query, Xbf);
  gemm_qkvz_kernel<<<dim3(8, 64), dim3(256), 0, stream>>>(
      Xbf, wbf + (size_t)0 * 1048576, bq, Qh, QSCALE);
  // k
  cast_x_kernel<<<dim3(8192), dim3(256), 0, stream>>>(key, Xbf);
  gemm_qkvz_kernel<<<dim3(8, 64), dim3(256), 0, stream>>>(
      Xbf, wbf + (size_t)1 * 1048576, bk, Kh, 1.0f);
  // v
  cast_x_kernel<<<dim3(8192), dim3(256), 0, stream>>>(value, Xbf);
  gemm_qkvz_kernel<<<dim3(8, 64), dim3(256), 0, stream>>>(
      Xbf, wbf + (size_t)2 * 1048576, bv, Vh, 1.0f);

  attn_kernel<<<dim3(8, 64), dim3(512), 0, stream>>>(Qh, Kh, Vh, AO);
  gemm_out_kernel<<<dim3(8, 64), dim3(256), 0, stream>>>(
      AO, wbf + (size_t)3 * 1048576, bo, (float*)d_out);
}

// Round 14
// 217.394 us; speedup vs baseline: 1.0559x; 1.0559x over previous
//
#include <hip/hip_runtime.h>
#include <hip/hip_bf16.h>
#include <stdint.h>

// MHA fused pipeline, MI355X gfx950.
// B=4 S=2048 D=1024 H=16 DK=64.  fp32 in/out, bf16 MFMA internally.
//
// ws layout (bytes):
//   [0,        8388608)   wbf   : bf16 weights [4][1024][1024] order q,k,v,o
//   [8388608,  25165824)  Qh    : bf16 [B,H,S,DK]  (Q pre-scaled by 0.125*log2e)
//   [25165824, 41943040)  Kh    : bf16 [B,H,S,DK]
//   [41943040, 58720256)  Vh    : bf16 [B,H,S,DK]
//   [58720256, 75497472)  AO    : bf16, DUAL USE: Xq-bf16 staging, then attn out
// d_out (32MB fp32) is used as scratch for Xk/Xv bf16 (16MB each) during the
// QKV phase; fully overwritten by gemm_out at the end (deterministic).
//
// XCD note: with gridDim.x==8, blockIdx.x == lin%8 selects the XCD; blocks
// sharing an A panel co-reside on one XCD (panel L2-hit). (round-6 win)
//
// NUMERICS: ALL f32->bf16 casts use explicit RNE bit math (== __float2bfloat16
// for finite inputs). v_cvt_pk_bf16_f32 is NOT RNE and fails even for the
// attention P-pack (round-13: truncation noise is 2x RNE and does not cancel
// in the softmax ratio -> absmax 1.8e-3 > 1.66e-3). RULE#20: no runtime-
// indexed register arrays (round-8 regression).
// Softmax denominator = MFMA row-sum (ones-B) of the SAME rounded P as the
// numerator: consistent ratio, no serial VALU adds, shuffle-free epilogue.

using f32x4  = __attribute__((ext_vector_type(4))) float;
using f32x16 = __attribute__((ext_vector_type(16))) float;
using s16x8  = __attribute__((ext_vector_type(8))) short;
using u16x8  = __attribute__((ext_vector_type(8))) unsigned short;
using u16x4  = __attribute__((ext_vector_type(4))) unsigned short;

#define MFMA16(a, b, c) __builtin_amdgcn_mfma_f32_16x16x32_bf16((a), (b), (c), 0, 0, 0)
#define MFMA32(a, b, c) __builtin_amdgcn_mfma_f32_32x32x16_bf16((a), (b), (c), 0, 0, 0)

#define GLL16(gptr, lptr)                                                      \
  __builtin_amdgcn_global_load_lds(                                            \
      (const __attribute__((address_space(1))) void*)(gptr),                   \
      (__attribute__((address_space(3))) void*)(lptr), 16, 0, 0)

__device__ __forceinline__ unsigned short f2bf(float f) {
  union { __hip_bfloat16 h; unsigned short u; } cv;
  cv.h = __float2bfloat16(f);
  return cv.u;
}

// explicit RNE f32->bf16 pair pack (bit-identical to __float2bfloat16, finite)
__device__ __forceinline__ unsigned int pkrne(float a, float b) {
  unsigned int ua = __builtin_bit_cast(unsigned int, a);
  unsigned int ub = __builtin_bit_cast(unsigned int, b);
  ua = ua + 0x7FFFu + ((ua >> 16) & 1u);
  ub = ub + 0x7FFFu + ((ub >> 16) & 1u);
  return (ua >> 16) | (ub & 0xFFFF0000u);
}

__device__ __forceinline__ float exp2a(float x) {
  return __builtin_amdgcn_exp2f(x);
}

// ---------------------------------------------------------------- cast weights
__global__ __launch_bounds__(256) void cast_w_kernel(
    const float* __restrict__ wq, const float* __restrict__ wk,
    const float* __restrict__ wv, const float* __restrict__ wo,
    unsigned short* __restrict__ dst) {
  int i = blockIdx.x * 256 + threadIdx.x;  // float4 index, total 1M
  int m = i >> 18;
  int off = i & 0x3FFFF;
  const float* src = (m == 0) ? wq : (m == 1) ? wk : (m == 2) ? wv : wo;
  float4 v = reinterpret_cast<const float4*>(src)[off];
  u16x4 o;
  o[0] = f2bf(v.x); o[1] = f2bf(v.y); o[2] = f2bf(v.z); o[3] = f2bf(v.w);
  *reinterpret_cast<u16x4*>(dst + (size_t)i * 4) = o;
}

// ------------------------------------------------------------ cast activations
// all three X inputs in one launch: grid (8192, 3).
__global__ __launch_bounds__(256) void cast_x3_kernel(
    const float* __restrict__ q, const float* __restrict__ k,
    const float* __restrict__ v, unsigned short* __restrict__ xq,
    unsigned short* __restrict__ xk, unsigned short* __restrict__ xv) {
  const int z = blockIdx.y;
  const float* src = (z == 0) ? q : (z == 1) ? k : v;
  unsigned short* dst = (z == 0) ? xq : (z == 1) ? xk : xv;
  int i = blockIdx.x * 256 + threadIdx.x;  // float4 index
  float4 f = reinterpret_cast<const float4*>(src)[i];
  uint2 p;
  p.x = pkrne(f.x, f.y);
  p.y = pkrne(f.z, f.w);
  *reinterpret_cast<uint2*>(dst + (size_t)i * 4) = p;
}

// --------------------------------------------------------- QKV projection (bf16)
// C = Xbf(bf16)[8192,1024] @ W(bf16,[N,K]) + bias -> [B,H,S,DK] bf16 scatter.
// BK=64, GLL16 both operands, chunk swizzle phys = logical ^ (row&7) -> zero
// bank conflicts (round-10 verified). grid (8,64,3): z selects q/k/v.
__global__ __launch_bounds__(256) void gemm_qkv_kernel(
    const unsigned short* __restrict__ Xq, const unsigned short* __restrict__ Xk,
    const unsigned short* __restrict__ Xv, const unsigned short* __restrict__ wbf,
    const float* __restrict__ bq, const float* __restrict__ bk,
    const float* __restrict__ bv, unsigned short* __restrict__ Qh,
    unsigned short* __restrict__ Kh, unsigned short* __restrict__ Vh) {
  const int z = blockIdx.z;
  const unsigned short* Xbf = (z == 0) ? Xq : (z == 1) ? Xk : Xv;
  const unsigned short* W = wbf + (size_t)z * 1048576;
  const float* bias = (z == 0) ? bq : (z == 1) ? bk : bv;
  unsigned short* dst = (z == 0) ? Qh : (z == 1) ? Kh : Vh;
  const float qscale = (z == 0) ? 0.18033688011112042f : 1.0f;  // 0.125*log2e

  __shared__ __align__(16) unsigned short Asm_[128 * 64];
  __shared__ __align__(16) unsigned short Bsm_[128 * 64];

  const int t = threadIdx.x;
  const int lane = t & 63, w = t >> 6;
  const int g = lane >> 4, c = lane & 15;
  const int wm = (w >> 1) * 64, wn = (w & 1) * 64;
  const int n0 = (blockIdx.y & 7) * 128;
  const int m0 = (blockIdx.x * 8 + (blockIdx.y >> 3)) * 128;

  f32x4 acc[4][4];
#pragma unroll
  for (int i = 0; i < 4; i++)
#pragma unroll
    for (int j = 0; j < 4; j++) acc[i][j] = (f32x4)0.0f;

  const int blr = lane >> 3;
  const int bgc = (lane & 7) ^ blr;

  for (int kt = 0; kt < 16; ++kt) {
    const int k0 = kt * 64;
    __syncthreads();
#pragma unroll
    for (int i = 0; i < 4; i++) {
      int ii = w * 4 + i;
      const unsigned short* ga = Xbf + (size_t)(m0 + ii * 8 + blr) * 1024 + k0 + bgc * 8;
      GLL16(ga, &Asm_[ii * 512]);
      const unsigned short* gb = W + (size_t)(n0 + ii * 8 + blr) * 1024 + k0 + bgc * 8;
      GLL16(gb, &Bsm_[ii * 512]);
    }
    __syncthreads();

#pragma unroll
    for (int ks = 0; ks < 2; ks++) {
      s16x8 af[4], bfr[4];
#pragma unroll
      for (int mt = 0; mt < 4; mt++) {
        int r = wm + mt * 16 + c;
        af[mt] = *reinterpret_cast<const s16x8*>(&Asm_[r * 64 + (((ks * 4 + g) ^ (c & 7)) << 3)]);
      }
#pragma unroll
      for (int nt = 0; nt < 4; nt++) {
        int r = wn + nt * 16 + c;
        bfr[nt] = *reinterpret_cast<const s16x8*>(&Bsm_[r * 64 + (((ks * 4 + g) ^ (c & 7)) << 3)]);
      }
#pragma unroll
      for (int mt = 0; mt < 4; mt++)
#pragma unroll
        for (int nt = 0; nt < 4; nt++)
          acc[mt][nt] = MFMA16(af[mt], bfr[nt], acc[mt][nt]);
    }
  }

  // epilogue: +bias, *qscale, scatter to [B,H,S,DK] bf16
#pragma unroll
  for (int mt = 0; mt < 4; mt++)
#pragma unroll
    for (int nt = 0; nt < 4; nt++) {
      int n = n0 + wn + nt * 16 + c;
      float bb = bias[n];
      int h = n >> 6, dk = n & 63;
#pragma unroll
      for (int r = 0; r < 4; r++) {
        int m = m0 + wm + mt * 16 + g * 4 + r;
        int b = m >> 11, s = m & 2047;
        dst[(((size_t)b * 16 + h) * 2048 + s) * 64 + dk] =
            f2bf((acc[mt][nt][r] + bb) * qscale);
      }
    }
}

// ----------------------------------------------------------- output projection
// out(fp32)[8192,1024] = AO(bf16) @ Wo(bf16,[N,K]) + bo.  BK=64, GLL16 both.
__global__ __launch_bounds__(256) void gemm_out_kernel(
    const unsigned short* __restrict__ AO, const unsigned short* __restrict__ Wo,
    const float* __restrict__ bo, float* __restrict__ out) {
  __shared__ __align__(16) unsigned short Asm_[128 * 64];
  __shared__ __align__(16) unsigned short Bsm_[128 * 64];

  const int t = threadIdx.x;
  const int lane = t & 63, w = t >> 6;
  const int g = lane >> 4, c = lane & 15;
  const int wm = (w >> 1) * 64, wn = (w & 1) * 64;
  const int n0 = (blockIdx.y & 7) * 128;
  const int m0 = (blockIdx.x * 8 + (blockIdx.y >> 3)) * 128;

  f32x4 acc[4][4];
#pragma unroll
  for (int i = 0; i < 4; i++)
#pragma unroll
    for (int j = 0; j < 4; j++) acc[i][j] = (f32x4)0.0f;

  const int blr = lane >> 3;
  const int bgc = (lane & 7) ^ blr;

  for (int kt = 0; kt < 16; ++kt) {
    const int k0 = kt * 64;
    __syncthreads();
#pragma unroll
    for (int i = 0; i < 4; i++) {
      int ii = w * 4 + i;
      const unsigned short* ga = AO + (size_t)(m0 + ii * 8 + blr) * 1024 + k0 + bgc * 8;
      GLL16(ga, &Asm_[ii * 512]);
      const unsigned short* gb = Wo + (size_t)(n0 + ii * 8 + blr) * 1024 + k0 + bgc * 8;
      GLL16(gb, &Bsm_[ii * 512]);
    }
    __syncthreads();

#pragma unroll
    for (int ks = 0; ks < 2; ks++) {
      s16x8 af[4], bfr[4];
#pragma unroll
      for (int mt = 0; mt < 4; mt++) {
        int r = wm + mt * 16 + c;
        af[mt] = *reinterpret_cast<const s16x8*>(&Asm_[r * 64 + (((ks * 4 + g) ^ (c & 7)) << 3)]);
      }
#pragma unroll
      for (int nt = 0; nt < 4; nt++) {
        int r = wn + nt * 16 + c;
        bfr[nt] = *reinterpret_cast<const s16x8*>(&Bsm_[r * 64 + (((ks * 4 + g) ^ (c & 7)) << 3)]);
      }
#pragma unroll
      for (int mt = 0; mt < 4; mt++)
#pragma unroll
        for (int nt = 0; nt < 4; nt++)
          acc[mt][nt] = MFMA16(af[mt], bfr[nt], acc[mt][nt]);
    }
  }

#pragma unroll
  for (int mt = 0; mt < 4; mt++)
#pragma unroll
    for (int nt = 0; nt < 4; nt++) {
      int n = n0 + wn + nt * 16 + c;
      float bb = bo[n];
#pragma unroll
      for (int r = 0; r < 4; r++) {
        int m = m0 + wm + mt * 16 + g * 4 + r;
        out[(size_t)m * 1024 + n] = acc[mt][nt][r] + bb;
      }
    }
}

// ---------------------------------------------------------------- attention v6
// 8 waves x 32 q-rows = 256 q-rows/block. KV tiles of 64. mfma_32x32x16.
// Swapped QK^T (S^T = K·Q^T, scores lane-local). No max-sub; v_exp_f32 with
// log2e folded into Q. P pack: RNE (pkrne) + permlane32_swap. Softmax
// denominator = MFMA row-sum (ones-B) of the SAME rounded P -> consistent
// ratio, no serial adds, shuffle-free epilogue.
// K,V swizzled LDS (zero conflicts, round-9 static layout), double-buffered.
__global__ __launch_bounds__(512) void attn_kernel(
    const unsigned short* __restrict__ Qh, const unsigned short* __restrict__ Kh,
    const unsigned short* __restrict__ Vh, unsigned short* __restrict__ AO) {
  const int bh = blockIdx.x * 8 + (blockIdx.y >> 3);
  const int b = bh >> 4, h = bh & 15;
  const int q0 = (blockIdx.y & 7) * 256;
  const int t = threadIdx.x, lane = t & 63, w = t >> 6;
  const int lo = lane & 31, hi = lane >> 5;

  __shared__ __align__(16) unsigned short Ks[2][64 * 64];
  __shared__ __align__(16) unsigned short Vt[2][64 * 64];

  const size_t kvbase = (size_t)bh * 2048 * 64;

  s16x8 qb[4];
  {
    const unsigned short* qp = Qh + kvbase + (size_t)(q0 + w * 32 + lo) * 64;
#pragma unroll
    for (int ks = 0; ks < 4; ks++)
      qb[ks] = *reinterpret_cast<const s16x8*>(qp + ks * 16 + hi * 8);
  }

  // ones B-fragment (bf16 1.0 in all 8 slots)
  s16x8 onesb;
  {
    uint4 u;
    u.x = 0x3F803F80u; u.y = 0x3F803F80u; u.z = 0x3F803F80u; u.w = 0x3F803F80u;
    onesb = *reinterpret_cast<const s16x8*>(&u);
  }

  f32x16 oacc[2], lacc;
  oacc[0] = (f32x16)0.0f; oacc[1] = (f32x16)0.0f; lacc = (f32x16)0.0f;

  const int skrow = t >> 3, sks = t & 7;
  const int kgc = sks ^ (skrow & 7) ^ w;
  const int vkrow = t >> 3, vd0 = (t & 7) * 8;
  const int vwc = w ^ (t & 7);
  const int vcl = vkrow & 7;

  const int rx0 = (lo & 7) ^ (lo >> 3);
  const int rx1 = (lo & 7) ^ (4 | (lo >> 3));

  uint4 kk, vv;
  kk = *reinterpret_cast<const uint4*>(Kh + kvbase + (size_t)skrow * 64 + kgc * 8);
  vv = *reinterpret_cast<const uint4*>(Vh + kvbase + (size_t)vkrow * 64 + vd0);
  *reinterpret_cast<uint4*>(&Ks[0][(size_t)t * 8]) = kk;
  {
    const unsigned short* vs = reinterpret_cast<const unsigned short*>(&vv);
#pragma unroll
    for (int j = 0; j < 8; j++)
      Vt[0][(vd0 + j) * 64 + ((vwc ^ j) << 3) + vcl] = vs[j];
  }

  for (int it = 0; it < 32; ++it) {
    const int cur = it & 1, nxt = cur ^ 1;
    const bool more = (it < 31);
    if (more) {
      const int kv = (it + 1) * 64;
      kk = *reinterpret_cast<const uint4*>(Kh + kvbase + (size_t)(kv + skrow) * 64 + kgc * 8);
      vv = *reinterpret_cast<const uint4*>(Vh + kvbase + (size_t)(kv + vkrow) * 64 + vd0);
    }
    __syncthreads();

    // S^T = K·Q^T
    f32x16 st[2];
    st[0] = (f32x16)0.0f; st[1] = (f32x16)0.0f;
#pragma unroll
    for (int kb = 0; kb < 2; kb++) {
      const int rx = kb ? rx1 : rx0;
#pragma unroll
      for (int ks = 0; ks < 4; ks++) {
        s16x8 ka = *reinterpret_cast<const s16x8*>(
            &Ks[cur][(kb * 32 + lo) * 64 + (((ks * 2 + hi) ^ rx) << 3)]);
        st[kb] = MFMA32(ka, qb[ks], st[kb]);
      }
    }

    // p = 2^s -> RNE bf16 pack -> permlane swap -> PV A-frags
    s16x8 pa[4];
#pragma unroll
    for (int kb = 0; kb < 2; kb++) {
      float e[16];
#pragma unroll
      for (int r = 0; r < 16; r++) e[r] = exp2a(st[kb][r]);
#pragma unroll
      for (int half = 0; half < 2; half++) {
        const float* eb = e + half * 8;
        unsigned int x1 = pkrne(eb[0], eb[1]);
        unsigned int x2 = pkrne(eb[2], eb[3]);
        unsigned int y1 = pkrne(eb[4], eb[5]);
        unsigned int y2 = pkrne(eb[6], eb[7]);
        asm volatile("v_permlane32_swap_b32 %0, %1" : "+v"(x1), "+v"(y1));
        asm volatile("v_permlane32_swap_b32 %0, %1" : "+v"(x2), "+v"(y2));
        uint4 u;
        u.x = x1; u.y = x2; u.z = y1; u.w = y2;
        pa[kb * 2 + half] = *reinterpret_cast<const s16x8*>(&u);
      }
    }

    // denominator: row-sum of packed P via MFMA (same values as numerator)
#pragma unroll
    for (int ks = 0; ks < 4; ks++) lacc = MFMA32(pa[ks], onesb, lacc);

    // stage next tile
    if (more) {
      *reinterpret_cast<uint4*>(&Ks[nxt][(size_t)t * 8]) = kk;
      const unsigned short* vs = reinterpret_cast<const unsigned short*>(&vv);
#pragma unroll
      for (int j = 0; j < 8; j++)
        Vt[nxt][(vd0 + j) * 64 + ((vwc ^ j) << 3) + vcl] = vs[j];
    }

    // O += P·V
#pragma unroll
    for (int ks = 0; ks < 4; ks++)
#pragma unroll
      for (int db = 0; db < 2; db++) {
        const int rx = db ? rx1 : rx0;
        s16x8 vb = *reinterpret_cast<const s16x8*>(
            &Vt[cur][(db * 32 + lo) * 64 + (((ks * 2 + hi) ^ rx) << 3)]);
        oacc[db] = MFMA32(pa[ks], vb, oacc[db]);
      }
  }

  // epilogue: normalize by lacc (same row layout as oacc), write AO bf16
#pragma unroll
  for (int r = 0; r < 16; r++) {
    float inv_r = 1.0f / lacc[r];
    int qr = (r & 3) + ((r >> 2) << 3) + (hi << 2);
    int srow = q0 + w * 32 + qr;
    size_t obase = ((size_t)b * 2048 + srow) * 1024 + (size_t)h * 64;
    AO[obase + lo]      = f2bf(oacc[0][r] * inv_r);
    AO[obase + 32 + lo] = f2bf(oacc[1][r] * inv_r);
  }
}

// ---------------------------------------------------------------- launcher
extern "C" void kernel_launch(void* const* d_in, const int* in_sizes, int n_in,
                              void* d_out, int out_size, void* d_ws, size_t ws_size,
                              hipStream_t stream) {
  const float* query = (const float*)d_in[0];
  const float* key   = (const float*)d_in[1];
  const float* value = (const float*)d_in[2];
  const float* Wq = (const float*)d_in[3];
  const float* bq = (const float*)d_in[4];
  const float* Wk = (const float*)d_in[5];
  const float* bk = (const float*)d_in[6];
  const float* Wv = (const float*)d_in[7];
  const float* bv = (const float*)d_in[8];
  const float* Wo = (const float*)d_in[9];
  const float* bo = (const float*)d_in[10];

  uint8_t* wsb = (uint8_t*)d_ws;
  unsigned short* wbf = (unsigned short*)wsb;                      // 4 x 1M bf16
  unsigned short* Qh  = (unsigned short*)(wsb + 8388608);
  unsigned short* Kh  = (unsigned short*)(wsb + 8388608 + 16777216);
  unsigned short* Vh  = (unsigned short*)(wsb + 8388608 + 2 * 16777216);
  unsigned short* AO  = (unsigned short*)(wsb + 8388608 + 3 * 16777216);
  // bf16 X staging: Xq in AO region; Xk/Xv in d_out (32MB, scratch until
  // gemm_out fully overwrites it)
  unsigned short* Xq = AO;
  unsigned short* Xk = (unsigned short*)d_out;
  unsigned short* Xv = (unsigned short*)d_out + 8388608;

  cast_w_kernel<<<dim3(4096), dim3(256), 0, stream>>>(Wq, Wk, Wv, Wo, wbf);
  cast_x3_kernel<<<dim3(8192, 3), dim3(256), 0, stream>>>(
      query, key, value, Xq, Xk, Xv);
  gemm_qkv_kernel<<<dim3(8, 64, 3), dim3(256), 0, stream>>>(
      Xq, Xk, Xv, wbf, bq, bk, bv, Qh, Kh, Vh);
  attn_kernel<<<dim3(8, 64), dim3(512), 0, stream>>>(Qh, Kh, Vh, AO);
  gemm_out_kernel<<<dim3(8, 64), dim3(256), 0, stream>>>(
      AO, wbf + (size_t)3 * 1048576, bo, (float*)d_out);
}